// Round 12
// baseline (372.291 us; speedup 1.0000x reference)
//
#include <hip/hip_runtime.h>
#include <hip/hip_bf16.h>

#define NE 4
#define HD 768
#define F2 384
#define F1 192
#define NT 131072

typedef __attribute__((ext_vector_type(8))) short bf16x8;
typedef __attribute__((ext_vector_type(4))) float f32x4;
typedef __attribute__((ext_vector_type(4))) unsigned int u32x4;

// ws layout (bytes)
#define WS_BUCKET_OFF 256
#define WS_B1S_OFF  (WS_BUCKET_OFF + NE*NT*4)            // 2,097,408
#define WS_DN2S_OFF (WS_B1S_OFF + NE*2*24*16384)         // +3,145,728
#define WS_ACT_OFF  (WS_DN2S_OFF + NE*4*6*16384)         // +1,572,864 ; act = NT*F1*2 -> ~57.1MB total
// b1s : [e][slice2][kstep24] 16KB image (12KB data+4KB pad); unit L(16B): colp=L>>3,slot=L&7,
//       v=slot^(colp&7), localcol=colp*2+(v>>2) in [0,192), k=kstep*32+(v&3)*8,
//       globalcol = lc<96 ? s*96+lc : 192+s*96+(lc-96)
// dn2s: [e][sl4][kt6] 16KB image; localcol -> outcol sl*192+lc, k=f=kt*32+(v&3)*8

// LDS both kernels: B quad-buffer 4x16KB + tok
#define LTOK 65536u
#define SMEM_BYTES 66048

__device__ __forceinline__ unsigned short f2bf(float x) {
    unsigned int u = __float_as_uint(x);
    return (unsigned short)((u + 0x7fffu + ((u >> 16) & 1u)) >> 16);
}
__device__ __forceinline__ unsigned int pk2(float a, float b) {
    unsigned int ua = __float_as_uint(a), ub = __float_as_uint(b);
    unsigned int lo = (ua + 0x7fffu + ((ua >> 16) & 1u)) >> 16;
    unsigned int hi = (ub + 0x7fffu + ((ub >> 16) & 1u)) & 0xffff0000u;
    return lo | hi;
}
#define GLL(srcp, ldsoff) \
    __builtin_amdgcn_global_load_lds((const __attribute__((address_space(1))) void*)(srcp), \
        (__attribute__((address_space(3))) void*)(smem + (ldsoff)), 16, 0, 0)

__global__ void route_kernel(const int* __restrict__ ids, int* __restrict__ counts,
                             int* __restrict__ bucket) {
    __shared__ int lc[NE];
    __shared__ int lb[NE];
    int tid = threadIdx.x;
    if (tid < NE) lc[tid] = 0;
    __syncthreads();
    int t = blockIdx.x * blockDim.x + tid;
    int e = ids[t];
    int rank = atomicAdd(&lc[e], 1);
    __syncthreads();
    if (tid < NE) lb[tid] = atomicAdd(&counts[tid], lc[tid]);
    __syncthreads();
    bucket[e * NT + lb[e] + rank] = t;
}

__global__ void b1s_kernel(const float* __restrict__ gu, unsigned short* __restrict__ b1s) {
    int idx = blockIdx.x * 256 + threadIdx.x;      // NE*2*24*768 = 147456
    int L = idx % 768; int r = idx / 768;
    int kstep = r % 24; r /= 24;
    int s = r & 1; int e = r >> 1;
    int colp = L >> 3, slot = L & 7;
    int v = slot ^ (colp & 7);
    int lc = colp * 2 + (v >> 2);
    int kb = kstep * 32 + (v & 3) * 8;
    int gc = (lc < 96) ? (s * 96 + lc) : (192 + s * 96 + (lc - 96));
    const float* src = gu + ((size_t)(e * HD + kb)) * F2 + gc;
    unsigned short o[8];
    #pragma unroll
    for (int j = 0; j < 8; ++j) o[j] = f2bf(src[(size_t)j * F2]);
    *(bf16x8*)(b1s + (((size_t)(e * 2 + s) * 24 + kstep) * 1024 + L) * 8) = *(const bf16x8*)o;
}

__global__ void dn2s_kernel(const float* __restrict__ dn, unsigned short* __restrict__ dn2s) {
    int idx = blockIdx.x * 256 + threadIdx.x;      // NE*4*6*768 = 73728
    int L = idx % 768; int r = idx / 768;
    int kt = r % 6; r /= 6;
    int sl = r & 3; int e = r >> 2;
    int colp = L >> 3, slot = L & 7;
    int v = slot ^ (colp & 7);
    int lc = colp * 2 + (v >> 2);
    int kb = kt * 32 + (v & 3) * 8;                // f index
    const float* src = dn + ((size_t)(e * F1 + kb)) * HD + sl * 192 + lc;
    unsigned short o[8];
    #pragma unroll
    for (int j = 0; j < 8; ++j) o[j] = f2bf(src[(size_t)j * HD]);
    *(bf16x8*)(dn2s + (((size_t)(e * 4 + sl) * 6 + kt) * 1024 + L) * 8) = *(const bf16x8*)o;
}

// =============== GEMM1: act[t][s*96..+96) = silu(h Wg)*(h Wu), TT=128, f-slice 96 ===============
__global__ __launch_bounds__(512, 2)
void gemm1_kernel(const float* __restrict__ hidden, const int* __restrict__ counts,
                  const int* __restrict__ bucket, const unsigned short* __restrict__ b1s,
                  unsigned short* __restrict__ act)
{
    extern __shared__ __align__(16) unsigned char smem[];
    const unsigned LBo[4] = {0u, 16384u, 32768u, 49152u};

    int bid = blockIdx.x;
    int swz = (bid & 7) * 257 + (bid >> 3);        // grid 2056 = 8*257, bijective
    int s = swz & 1, tile = swz >> 1;
    int rem = tile, e, n_e = 0;
    for (e = 0; e < NE; ++e) {
        n_e = counts[e];
        int nt_ = (n_e + 127) >> 7;
        if (rem < nt_) break;
        rem -= nt_;
    }
    if (e >= NE) return;
    int t0 = rem << 7;

    int tid = threadIdx.x, lane = tid & 63, w = tid >> 6;
    int lg = lane >> 4, l16 = lane & 15;

    int* tokp = (int*)(smem + LTOK);
    if (tid < 128) {
        int idx = t0 + tid; if (idx >= n_e) idx = n_e - 1;
        tokp[tid] = bucket[e * NT + idx];
    }
    __syncthreads();

    // A direct: lane (l16=row, lg=k-octet) reads hidden[tok[w*16+l16]][g*32+lg*8 ..]
    const float* aptr = hidden + (size_t)tokp[w * 16 + l16] * HD + lg * 8;
    // B GLL: per wave 2 chunks of 1KB from padded 16KB step-image
    const unsigned short* gb = b1s + (size_t)(e * 2 + s) * 24 * 8192 + (w * 2) * 512 + lane * 8;
    unsigned gld = (unsigned)(w * 2) * 1024u;
    unsigned laneoff = (unsigned)(((l16 >> 1) << 7) +
                       (((lg + ((l16 & 1) << 2)) ^ (l16 >> 1)) << 4));

    f32x4 ar[3][2];
    const f32x4 fzero = {0.f, 0.f, 0.f, 0.f};
    f32x4 acc[12];
    #pragma unroll
    for (int nt = 0; nt < 12; ++nt) acc[nt] = fzero;

    // prologue: B0,A0,B1,A1,B2,A2
    GLL(gb, LBo[0] + gld); GLL(gb + 512, LBo[0] + gld + 1024u);
    { const f32x4* p = (const f32x4*)(aptr); ar[0][0] = p[0]; ar[0][1] = p[1]; }
    GLL(gb + 8192, LBo[1] + gld); GLL(gb + 8192 + 512, LBo[1] + gld + 1024u);
    { const f32x4* p = (const f32x4*)(aptr + 32); ar[1][0] = p[0]; ar[1][1] = p[1]; }
    GLL(gb + 16384, LBo[2] + gld); GLL(gb + 16384 + 512, LBo[2] + gld + 1024u);
    { const f32x4* p = (const f32x4*)(aptr + 64); ar[2][0] = p[0]; ar[2][1] = p[1]; }
    asm volatile("s_waitcnt vmcnt(10) lgkmcnt(0)");   // B0 done; rest in flight
    __builtin_amdgcn_s_barrier();
    __builtin_amdgcn_sched_barrier(0);

    #pragma unroll
    for (int g = 0; g < 24; ++g) {
        // convert A(g) (compiler inserts counted vmcnt for ar[g%3] only)
        f32x4 a0 = ar[g % 3][0], a1 = ar[g % 3][1];
        u32x4 cv = {pk2(a0.x, a0.y), pk2(a0.z, a0.w), pk2(a1.x, a1.y), pk2(a1.z, a1.w)};
        bf16x8 afr = __builtin_bit_cast(bf16x8, cv);

        if (g < 21) {   // issue B(g+3) then A(g+3)
            GLL(gb + (size_t)(g + 3) * 8192, LBo[(g + 3) & 3] + gld);
            GLL(gb + (size_t)(g + 3) * 8192 + 512, LBo[(g + 3) & 3] + gld + 1024u);
            const f32x4* p = (const f32x4*)(aptr + (g + 3) * 32);
            ar[g % 3][0] = p[0]; ar[g % 3][1] = p[1];
        }

        const unsigned char* bb = smem + LBo[g & 3] + laneoff;
        __builtin_amdgcn_s_setprio(1);
        #pragma unroll
        for (int nt = 0; nt < 12; ++nt) {
            bf16x8 Bf = *(const bf16x8*)(bb + nt * 1024);
            acc[nt] = __builtin_amdgcn_mfma_f32_16x16x32_bf16(afr, Bf, acc[nt], 0, 0, 0);
        }
        __builtin_amdgcn_s_setprio(0);

        if (g < 23) {
            if (g <= 20)      asm volatile("s_waitcnt vmcnt(10) lgkmcnt(0)");
            else if (g == 21) asm volatile("s_waitcnt vmcnt(6) lgkmcnt(0)");
            else              asm volatile("s_waitcnt vmcnt(2) lgkmcnt(0)");
            __builtin_amdgcn_s_barrier();
            __builtin_amdgcn_sched_barrier(0);
        }
    }

    // silu epilogue: acc[nt]=gate(local col nt*16+l16), acc[nt+6]=up -> act ws (bf16)
    #pragma unroll
    for (int nt = 0; nt < 6; ++nt)
        #pragma unroll
        for (int p = 0; p < 4; ++p) {
            int row = w * 16 + lg * 4 + p;
            if (t0 + row < n_e) {
                float g_ = acc[nt][p], u_ = acc[nt + 6][p];
                float a_ = g_ / (1.f + __expf(-g_)) * u_;
                act[(size_t)tokp[row] * F1 + s * 96 + nt * 16 + l16] = f2bf(a_);
            }
        }
}

// =============== GEMM2: out[t][sl*192..+192) = act[t][0..192) * down, TT=128 ===============
__global__ __launch_bounds__(512, 2)
void gemm2_kernel(const int* __restrict__ counts, const int* __restrict__ bucket,
                  const unsigned short* __restrict__ dn2s, const unsigned short* __restrict__ act,
                  float* __restrict__ out)
{
    extern __shared__ __align__(16) unsigned char smem[];
    const unsigned LBo[4] = {0u, 16384u, 32768u, 49152u};

    int bid = blockIdx.x;
    int swz = (bid & 7) * 514 + (bid >> 3);        // grid 4112 = 8*514
    int sl = swz & 3, tile = swz >> 2;
    int rem = tile, e, n_e = 0;
    for (e = 0; e < NE; ++e) {
        n_e = counts[e];
        int nt_ = (n_e + 127) >> 7;
        if (rem < nt_) break;
        rem -= nt_;
    }
    if (e >= NE) return;
    int t0 = rem << 7;

    int tid = threadIdx.x, lane = tid & 63, w = tid >> 6;
    int lg = lane >> 4, l16 = lane & 15;

    int* tokp = (int*)(smem + LTOK);
    if (tid < 128) {
        int idx = t0 + tid; if (idx >= n_e) idx = n_e - 1;
        tokp[tid] = bucket[e * NT + idx];
    }
    __syncthreads();

    // A direct from act (already bf16): lane(l16=row, lg=k-octet)
    const unsigned short* aptr = act + (size_t)tokp[w * 16 + l16] * F1 + lg * 8;
    const unsigned short* gb = dn2s + (size_t)(e * 4 + sl) * 6 * 8192 + (w * 2) * 512 + lane * 8;
    unsigned gld = (unsigned)(w * 2) * 1024u;
    unsigned laneoff = (unsigned)(((l16 >> 1) << 7) +
                       (((lg + ((l16 & 1) << 2)) ^ (l16 >> 1)) << 4));

    bf16x8 ar2[3];
    const f32x4 fzero = {0.f, 0.f, 0.f, 0.f};
    f32x4 acc[12];
    #pragma unroll
    for (int nt = 0; nt < 12; ++nt) acc[nt] = fzero;

    // prologue: B0,A0,B1,A1,B2,A2
    GLL(gb, LBo[0] + gld); GLL(gb + 512, LBo[0] + gld + 1024u);
    ar2[0] = *(const bf16x8*)(aptr);
    GLL(gb + 8192, LBo[1] + gld); GLL(gb + 8192 + 512, LBo[1] + gld + 1024u);
    ar2[1] = *(const bf16x8*)(aptr + 32);
    GLL(gb + 16384, LBo[2] + gld); GLL(gb + 16384 + 512, LBo[2] + gld + 1024u);
    ar2[2] = *(const bf16x8*)(aptr + 64);
    asm volatile("s_waitcnt vmcnt(7) lgkmcnt(0)");   // B0 done
    __builtin_amdgcn_s_barrier();
    __builtin_amdgcn_sched_barrier(0);

    #pragma unroll
    for (int kt = 0; kt < 6; ++kt) {
        bf16x8 afr = ar2[kt % 3];                   // compiler waits this load
        if (kt < 3) {
            GLL(gb + (size_t)(kt + 3) * 8192, LBo[(kt + 3) & 3] + gld);
            GLL(gb + (size_t)(kt + 3) * 8192 + 512, LBo[(kt + 3) & 3] + gld + 1024u);
            ar2[kt % 3] = *(const bf16x8*)(aptr + (kt + 3) * 32);
        }

        const unsigned char* bb = smem + LBo[kt & 3] + laneoff;
        __builtin_amdgcn_s_setprio(1);
        #pragma unroll
        for (int nt = 0; nt < 12; ++nt) {
            bf16x8 Bf = *(const bf16x8*)(bb + nt * 1024);
            acc[nt] = __builtin_amdgcn_mfma_f32_16x16x32_bf16(afr, Bf, acc[nt], 0, 0, 0);
        }
        __builtin_amdgcn_s_setprio(0);

        if (kt < 5) {
            if (kt <= 2)      asm volatile("s_waitcnt vmcnt(7) lgkmcnt(0)");
            else if (kt == 3) asm volatile("s_waitcnt vmcnt(4) lgkmcnt(0)");
            else              asm volatile("s_waitcnt vmcnt(1) lgkmcnt(0)");
            __builtin_amdgcn_s_barrier();
            __builtin_amdgcn_sched_barrier(0);
        }
    }

    #pragma unroll
    for (int nt = 0; nt < 12; ++nt)
        #pragma unroll
        for (int p = 0; p < 4; ++p) {
            int row = w * 16 + lg * 4 + p;
            if (t0 + row < n_e)
                out[(size_t)tokp[row] * HD + sl * 192 + nt * 16 + l16] = acc[nt][p];
        }
}

extern "C" void kernel_launch(void* const* d_in, const int* in_sizes, int n_in,
                              void* d_out, int out_size, void* d_ws, size_t ws_size,
                              hipStream_t stream) {
    (void)in_sizes; (void)n_in; (void)out_size; (void)ws_size;
    const float* hidden = (const float*)d_in[0];
    const int*   ids    = (const int*)d_in[1];
    const float* gu     = (const float*)d_in[2];
    const float* dn     = (const float*)d_in[3];
    float* out = (float*)d_out;

    char* ws = (char*)d_ws;
    int* counts = (int*)ws;
    int* bucket = (int*)(ws + WS_BUCKET_OFF);
    unsigned short* b1s  = (unsigned short*)(ws + WS_B1S_OFF);
    unsigned short* dn2s = (unsigned short*)(ws + WS_DN2S_OFF);
    unsigned short* actw = (unsigned short*)(ws + WS_ACT_OFF);

    hipMemsetAsync(d_ws, 0, 64, stream);
    route_kernel<<<NT / 256, 256, 0, stream>>>(ids, counts, bucket);
    b1s_kernel<<<576, 256, 0, stream>>>(gu, b1s);       // NE*2*24*768 units
    dn2s_kernel<<<288, 256, 0, stream>>>(dn, dn2s);     // NE*4*6*768 units
    gemm1_kernel<<<2056, 512, SMEM_BYTES, stream>>>(hidden, counts, bucket, b1s, actw);
    gemm2_kernel<<<4112, 512, SMEM_BYTES, stream>>>(counts, bucket, dn2s, actw, out);
}

// Round 13
// 370.517 us; speedup vs baseline: 1.0048x; 1.0048x over previous
//
#include <hip/hip_runtime.h>
#include <hip/hip_bf16.h>

#define NE 4
#define HD 768
#define F2 384
#define F1 192
#define NT 131072

typedef __attribute__((ext_vector_type(8))) short bf16x8;
typedef __attribute__((ext_vector_type(4))) float f32x4;
typedef __attribute__((ext_vector_type(4))) unsigned int u32x4;

// ws layout (bytes)
#define WS_BUCKET_OFF 256
#define WS_B1S_OFF  (WS_BUCKET_OFF + NE*NT*4)
#define WS_DN2S_OFF (WS_B1S_OFF + NE*2*24*16384)
#define WS_ACT_OFF  (WS_DN2S_OFF + NE*4*6*16384)
// b1s : [e][s2][kstep24] 16KB-stride image (12KB data); unit L(16B): colp=L>>3,slot=L&7,
//       v=slot^(colp&7), lc=colp*2+(v>>2) in [0,192), k=kstep*32+(v&3)*8,
//       globalcol = lc<96 ? s*96+lc : 192+s*96+(lc-96)
// dn2s: [e][sl4][kt6] 16KB-stride image; outcol sl*192+lc, k=f=kt*32+(v&3)*8

// LDS both kernels: B triple-buffer 3x24KB + tok(64)
#define LTOK 73728u
#define SMEM_BYTES 73984

__device__ __forceinline__ unsigned short f2bf(float x) {
    unsigned int u = __float_as_uint(x);
    return (unsigned short)((u + 0x7fffu + ((u >> 16) & 1u)) >> 16);
}
__device__ __forceinline__ unsigned int pk2(float a, float b) {
    unsigned int ua = __float_as_uint(a), ub = __float_as_uint(b);
    unsigned int lo = (ua + 0x7fffu + ((ua >> 16) & 1u)) >> 16;
    unsigned int hi = (ub + 0x7fffu + ((ub >> 16) & 1u)) & 0xffff0000u;
    return lo | hi;
}
#define GLL(srcp, ldsoff) \
    __builtin_amdgcn_global_load_lds((const __attribute__((address_space(1))) void*)(srcp), \
        (__attribute__((address_space(3))) void*)(smem + (ldsoff)), 16, 0, 0)

__global__ void route_kernel(const int* __restrict__ ids, int* __restrict__ counts,
                             int* __restrict__ bucket) {
    __shared__ int lc[NE];
    __shared__ int lb[NE];
    int tid = threadIdx.x;
    if (tid < NE) lc[tid] = 0;
    __syncthreads();
    int t = blockIdx.x * blockDim.x + tid;
    int e = ids[t];
    int rank = atomicAdd(&lc[e], 1);
    __syncthreads();
    if (tid < NE) lb[tid] = atomicAdd(&counts[tid], lc[tid]);
    __syncthreads();
    bucket[e * NT + lb[e] + rank] = t;
}

__global__ void b1s_kernel(const float* __restrict__ gu, unsigned short* __restrict__ b1s) {
    int idx = blockIdx.x * 256 + threadIdx.x;      // NE*2*24*768 = 147456
    int L = idx % 768; int r = idx / 768;
    int kstep = r % 24; r /= 24;
    int s = r & 1; int e = r >> 1;
    int colp = L >> 3, slot = L & 7;
    int v = slot ^ (colp & 7);
    int lc = colp * 2 + (v >> 2);
    int kb = kstep * 32 + (v & 3) * 8;
    int gc = (lc < 96) ? (s * 96 + lc) : (192 + s * 96 + (lc - 96));
    const float* src = gu + ((size_t)(e * HD + kb)) * F2 + gc;
    unsigned short o[8];
    #pragma unroll
    for (int j = 0; j < 8; ++j) o[j] = f2bf(src[(size_t)j * F2]);
    *(bf16x8*)(b1s + (((size_t)(e * 2 + s) * 24 + kstep) * 8192 + (size_t)L * 8)) = *(const bf16x8*)o;
}

__global__ void dn2s_kernel(const float* __restrict__ dn, unsigned short* __restrict__ dn2s) {
    int idx = blockIdx.x * 256 + threadIdx.x;      // NE*4*6*768 = 73728
    int L = idx % 768; int r = idx / 768;
    int kt = r % 6; r /= 6;
    int sl = r & 3; int e = r >> 2;
    int colp = L >> 3, slot = L & 7;
    int v = slot ^ (colp & 7);
    int lc = colp * 2 + (v >> 2);
    int kb = kt * 32 + (v & 3) * 8;
    const float* src = dn + ((size_t)(e * F1 + kb)) * HD + sl * 192 + lc;
    unsigned short o[8];
    #pragma unroll
    for (int j = 0; j < 8; ++j) o[j] = f2bf(src[(size_t)j * HD]);
    *(bf16x8*)(dn2s + (((size_t)(e * 4 + sl) * 6 + kt) * 8192 + (size_t)L * 8)) = *(const bf16x8*)o;
}

// ======= GEMM1: act[64 tok][all 384 f] ; 8 waves = 4 row-groups x 2 f-slices =======
__global__ __launch_bounds__(512, 2)
void gemm1_kernel(const float* __restrict__ hidden, const int* __restrict__ counts,
                  const int* __restrict__ bucket, const unsigned short* __restrict__ b1s,
                  unsigned short* __restrict__ act)
{
    extern __shared__ __align__(16) unsigned char smem[];
    const unsigned LBo[3] = {0u, 24576u, 49152u};

    int bid = blockIdx.x;
    int swz = (bid & 7) * 257 + (bid >> 3);        // grid 2056 = 8*257, bijective
    int rem = swz, e, n_e = 0;
    for (e = 0; e < NE; ++e) {
        n_e = counts[e];
        int nt_ = (n_e + 63) >> 6;
        if (rem < nt_) break;
        rem -= nt_;
    }
    if (e >= NE) return;
    int t0 = rem << 6;

    int tid = threadIdx.x, lane = tid & 63, w = tid >> 6;
    int rg = w & 3, s = w >> 2;
    int lg = lane >> 4, l16 = lane & 15;

    int* tokp = (int*)(smem + LTOK);
    if (tid < 64) {
        int idx = t0 + tid; if (idx >= n_e) idx = n_e - 1;
        tokp[tid] = bucket[e * NT + idx];
    }
    __syncthreads();

    // A direct: lane(l16=row-in-group, lg=k-octet)
    const float* aptr = hidden + (size_t)tokp[rg * 16 + l16] * HD + lg * 8;
    // B GLL: wave handles 3 chunks of its slice's 12KB image half
    const unsigned short* gb = b1s + (size_t)(e * 2 + s) * 24 * 8192 + (rg * 3) * 512 + lane * 8;
    unsigned gdst = (unsigned)(s * 12288 + rg * 3 * 1024);
    unsigned laneoff = (unsigned)(s * 12288) + (unsigned)(((l16 >> 1) << 7) +
                       (((lg + ((l16 & 1) << 2)) ^ (l16 >> 1)) << 4));

    f32x4 ar[3][2];
    const f32x4 fzero = {0.f, 0.f, 0.f, 0.f};
    f32x4 acc[12];
    #pragma unroll
    for (int nt = 0; nt < 12; ++nt) acc[nt] = fzero;

    // prologue: A0,A1,A2 (deep), B0,B1 (2 bufs)
    #pragma unroll
    for (int j = 0; j < 3; ++j) {
        const f32x4* p = (const f32x4*)(aptr + j * 32);
        ar[j][0] = p[0]; ar[j][1] = p[1];
    }
    #pragma unroll
    for (int i = 0; i < 3; ++i) GLL(gb + i * 512, LBo[0] + gdst + i * 1024u);
    #pragma unroll
    for (int i = 0; i < 3; ++i) GLL(gb + 8192 + i * 512, LBo[1] + gdst + i * 1024u);
    asm volatile("s_waitcnt vmcnt(3) lgkmcnt(0)");   // B0 done; B1 in flight
    __builtin_amdgcn_s_barrier();
    __builtin_amdgcn_sched_barrier(0);

    #pragma unroll
    for (int g = 0; g < 24; ++g) {
        // consume A(g) (compiler inserts its own counted wait)
        f32x4 a0 = ar[g % 3][0], a1 = ar[g % 3][1];
        u32x4 cv = {pk2(a0.x, a0.y), pk2(a0.z, a0.w), pk2(a1.x, a1.y), pk2(a1.z, a1.w)};
        bf16x8 afr = __builtin_bit_cast(bf16x8, cv);

        if (g < 21) {       // A(g+3) (issued BEFORE B so counted waits are reorder-proof)
            const f32x4* p = (const f32x4*)(aptr + (g + 3) * 32);
            ar[g % 3][0] = p[0]; ar[g % 3][1] = p[1];
        }
        if (g < 22) {       // B(g+2) -> buf[(g+2)%3] (consumed two steps ago: free)
            #pragma unroll
            for (int i = 0; i < 3; ++i)
                GLL(gb + (size_t)(g + 2) * 8192 + i * 512, LBo[(g + 2) % 3] + gdst + i * 1024u);
        }

        const unsigned char* bb = smem + LBo[g % 3] + laneoff;
        __builtin_amdgcn_s_setprio(1);
        #pragma unroll
        for (int nt = 0; nt < 12; ++nt) {
            bf16x8 Bf = *(const bf16x8*)(bb + nt * 1024);
            acc[nt] = __builtin_amdgcn_mfma_f32_16x16x32_bf16(afr, Bf, acc[nt], 0, 0, 0);
        }
        __builtin_amdgcn_s_setprio(0);

        if (g < 23) {
            if (g <= 20)      asm volatile("s_waitcnt vmcnt(5) lgkmcnt(0)");  // B(g+1) done
            else if (g == 21) asm volatile("s_waitcnt vmcnt(3) lgkmcnt(0)");
            else              asm volatile("s_waitcnt vmcnt(0) lgkmcnt(0)");
            __builtin_amdgcn_s_barrier();
            __builtin_amdgcn_sched_barrier(0);
        }
    }

    // silu epilogue: acc[nt]=gate(f=s*96+nt*16+l16), acc[nt+6]=up -> act (bf16)
    #pragma unroll
    for (int nt = 0; nt < 6; ++nt)
        #pragma unroll
        for (int p = 0; p < 4; ++p) {
            int row = rg * 16 + lg * 4 + p;
            if (t0 + row < n_e) {
                float g_ = acc[nt][p], u_ = acc[nt + 6][p];
                float a_ = g_ / (1.f + __expf(-g_)) * u_;
                act[(size_t)tokp[row] * F1 + s * 96 + nt * 16 + l16] = f2bf(a_);
            }
        }
}

// ======= GEMM2: out[64 tok][half*384 .. +384) ; 8 waves = 4 row-groups x 2 slices =======
__global__ __launch_bounds__(512, 2)
void gemm2_kernel(const int* __restrict__ counts, const int* __restrict__ bucket,
                  const unsigned short* __restrict__ dn2s, const unsigned short* __restrict__ act,
                  float* __restrict__ out)
{
    extern __shared__ __align__(16) unsigned char smem[];
    const unsigned LBo[3] = {0u, 24576u, 49152u};

    int bid = blockIdx.x;
    int swz = (bid & 7) * 514 + (bid >> 3);        // grid 4112 = 8*514
    int half = swz & 1, tile = swz >> 1;
    int rem = tile, e, n_e = 0;
    for (e = 0; e < NE; ++e) {
        n_e = counts[e];
        int nt_ = (n_e + 63) >> 6;
        if (rem < nt_) break;
        rem -= nt_;
    }
    if (e >= NE) return;
    int t0 = rem << 6;

    int tid = threadIdx.x, lane = tid & 63, w = tid >> 6;
    int rg = w & 3, s2 = w >> 2;
    int sl = half * 2 + s2;
    int lg = lane >> 4, l16 = lane & 15;

    int* tokp = (int*)(smem + LTOK);
    if (tid < 64) {
        int idx = t0 + tid; if (idx >= n_e) idx = n_e - 1;
        tokp[tid] = bucket[e * NT + idx];
    }
    __syncthreads();

    const unsigned short* aptr = act + (size_t)tokp[rg * 16 + l16] * F1 + lg * 8;
    const unsigned short* gb = dn2s + (size_t)(e * 4 + sl) * 6 * 8192 + (rg * 3) * 512 + lane * 8;
    unsigned gdst = (unsigned)(s2 * 12288 + rg * 3 * 1024);
    unsigned laneoff = (unsigned)(s2 * 12288) + (unsigned)(((l16 >> 1) << 7) +
                       (((lg + ((l16 & 1) << 2)) ^ (l16 >> 1)) << 4));

    bf16x8 ar2[3];
    const f32x4 fzero = {0.f, 0.f, 0.f, 0.f};
    f32x4 acc[12];
    #pragma unroll
    for (int nt = 0; nt < 12; ++nt) acc[nt] = fzero;

    // prologue: A0,A1,A2, B0,B1
    #pragma unroll
    for (int j = 0; j < 3; ++j) ar2[j] = *(const bf16x8*)(aptr + j * 32);
    #pragma unroll
    for (int i = 0; i < 3; ++i) GLL(gb + i * 512, LBo[0] + gdst + i * 1024u);
    #pragma unroll
    for (int i = 0; i < 3; ++i) GLL(gb + 8192 + i * 512, LBo[1] + gdst + i * 1024u);
    asm volatile("s_waitcnt vmcnt(3) lgkmcnt(0)");
    __builtin_amdgcn_s_barrier();
    __builtin_amdgcn_sched_barrier(0);

    #pragma unroll
    for (int kt = 0; kt < 6; ++kt) {
        bf16x8 afr = ar2[kt % 3];
        if (kt < 3) ar2[kt % 3] = *(const bf16x8*)(aptr + (kt + 3) * 32);
        if (kt < 4) {
            #pragma unroll
            for (int i = 0; i < 3; ++i)
                GLL(gb + (size_t)(kt + 2) * 8192 + i * 512, LBo[(kt + 2) % 3] + gdst + i * 1024u);
        }

        const unsigned char* bb = smem + LBo[kt % 3] + laneoff;
        __builtin_amdgcn_s_setprio(1);
        #pragma unroll
        for (int nt = 0; nt < 12; ++nt) {
            bf16x8 Bf = *(const bf16x8*)(bb + nt * 1024);
            acc[nt] = __builtin_amdgcn_mfma_f32_16x16x32_bf16(afr, Bf, acc[nt], 0, 0, 0);
        }
        __builtin_amdgcn_s_setprio(0);

        if (kt < 5) {
            if (kt <= 2)      asm volatile("s_waitcnt vmcnt(4) lgkmcnt(0)");  // B(kt+1) done
            else if (kt == 3) asm volatile("s_waitcnt vmcnt(3) lgkmcnt(0)");
            else              asm volatile("s_waitcnt vmcnt(0) lgkmcnt(0)");
            __builtin_amdgcn_s_barrier();
            __builtin_amdgcn_sched_barrier(0);
        }
    }

    #pragma unroll
    for (int nt = 0; nt < 12; ++nt)
        #pragma unroll
        for (int p = 0; p < 4; ++p) {
            int row = rg * 16 + lg * 4 + p;
            if (t0 + row < n_e)
                out[(size_t)tokp[row] * HD + sl * 192 + nt * 16 + l16] = acc[nt][p];
        }
}

extern "C" void kernel_launch(void* const* d_in, const int* in_sizes, int n_in,
                              void* d_out, int out_size, void* d_ws, size_t ws_size,
                              hipStream_t stream) {
    (void)in_sizes; (void)n_in; (void)out_size; (void)ws_size;
    const float* hidden = (const float*)d_in[0];
    const int*   ids    = (const int*)d_in[1];
    const float* gu     = (const float*)d_in[2];
    const float* dn     = (const float*)d_in[3];
    float* out = (float*)d_out;

    char* ws = (char*)d_ws;
    int* counts = (int*)ws;
    int* bucket = (int*)(ws + WS_BUCKET_OFF);
    unsigned short* b1s  = (unsigned short*)(ws + WS_B1S_OFF);
    unsigned short* dn2s = (unsigned short*)(ws + WS_DN2S_OFF);
    unsigned short* actw = (unsigned short*)(ws + WS_ACT_OFF);

    hipMemsetAsync(d_ws, 0, 64, stream);
    route_kernel<<<NT / 256, 256, 0, stream>>>(ids, counts, bucket);
    b1s_kernel<<<576, 256, 0, stream>>>(gu, b1s);
    dn2s_kernel<<<288, 256, 0, stream>>>(dn, dn2s);
    gemm1_kernel<<<2056, 512, SMEM_BYTES, stream>>>(hidden, counts, bucket, b1s, actw);
    gemm2_kernel<<<4112, 512, SMEM_BYTES, stream>>>(counts, bucket, dn2s, actw, out);
}